// Round 1
// baseline (31.937 us; speedup 1.0000x reference)
//
#include <hip/hip_runtime.h>

#define B_DIM 4096
#define L_DIM 512
#define NT 1000
#define OD 8

__global__ __launch_bounds__(256) void ste_kernel(
    const float* __restrict__ timestamp,   // (B, L+1)
    const float* __restrict__ W,           // (OD, NT)
    const float* __restrict__ bias,        // (OD,)
    float* __restrict__ out_te,            // (B, L, OD)
    float* __restrict__ out_ts)            // (B, L)
{
    // Build Wt[idx][j] = W[j][idx] + bias[j] in LDS: 1000 x 8 f32 = 32 KB.
    __shared__ float wt[NT * OD];
    for (int k = threadIdx.x; k < NT * OD; k += 256) {
        int row = k >> 3;   // idx
        int j   = k & 7;    // out dim
        wt[row * OD + j] = W[j * NT + row] + bias[j];
    }
    __syncthreads();

    const float4* wt4 = reinterpret_cast<const float4*>(wt);

    const int total  = B_DIM * L_DIM;
    const int stride = gridDim.x * blockDim.x;
    for (int e = blockIdx.x * blockDim.x + threadIdx.x; e < total; e += stride) {
        const int row = e >> 9;           // L == 512
        const int col = e & (L_DIM - 1);
        const float ts = timestamp[row * (L_DIM + 1) + col];

        out_ts[e] = ts;

        // idx = max(floor(ts / 1000.0), 0); exact IEEE f32 division to match
        // the numpy reference at bucket boundaries. Clamp high for safety
        // (jnp.take clamps OOB).
        float q = ts / 1000.0f;
        int idx = (int)floorf(q);
        idx = idx < 0 ? 0 : (idx > NT - 1 ? NT - 1 : idx);

        const float4 v0 = wt4[idx * 2 + 0];
        const float4 v1 = wt4[idx * 2 + 1];
        float4* o = reinterpret_cast<float4*>(out_te + (size_t)e * OD);
        o[0] = v0;
        o[1] = v1;
    }
}

extern "C" void kernel_launch(void* const* d_in, const int* in_sizes, int n_in,
                              void* d_out, int out_size, void* d_ws, size_t ws_size,
                              hipStream_t stream) {
    // Inputs (setup_inputs order): input (int32, unused), timestamp (f32),
    // W (f32, 8x1000), b (f32, 8).
    const float* timestamp = (const float*)d_in[1];
    const float* W         = (const float*)d_in[2];
    const float* bias      = (const float*)d_in[3];

    float* out = (float*)d_out;
    float* out_te = out;                                    // B*L*8 floats
    float* out_ts = out + (size_t)B_DIM * L_DIM * OD;       // B*L floats

    ste_kernel<<<2048, 256, 0, stream>>>(timestamp, W, bias, out_te, out_ts);
}